// Round 7
// baseline (316.768 us; speedup 1.0000x reference)
//
#include <hip/hip_runtime.h>
#include <hip/hip_fp16.h>

typedef _Float16 half_t;
typedef _Float16 half8 __attribute__((ext_vector_type(8)));
typedef float floatx4 __attribute__((ext_vector_type(4)));

static constexpr int BATCH = 2;
static constexpr int NSP = 4096;   // H*W
static constexpr int CH = 512;
static constexpr int NQKV = 3 * CH;  // 1536

// ---- ws layout (bytes) ----
static constexpr size_t OFF_STATS = 0;                              // 128 floats
static constexpr size_t OFF_ROWSUM = 512;                           // B*NSP floats (32 KB)
static constexpr size_t OFF_WQKV = 36864;
static constexpr size_t WQKV_BYTES = (size_t)NQKV * CH * 2;         // 1.5 MB
static constexpr size_t OFF_WP = OFF_WQKV + WQKV_BYTES;
static constexpr size_t WP_BYTES = (size_t)CH * CH * 2;             // 0.5 MB
static constexpr size_t OFF_XN = OFF_WP + WP_BYTES;
static constexpr size_t XN_BYTES = (size_t)BATCH * NSP * CH * 2;    // 8 MB
static constexpr size_t OFF_QKV = OFF_XN + XN_BYTES;
static constexpr size_t QKV_BYTES = (size_t)BATCH * NSP * NQKV * 2; // 24 MB
static constexpr size_t OFF_VT = OFF_QKV + QKV_BYTES;
static constexpr size_t OFF_AO = OFF_VT + XN_BYTES;
static constexpr size_t OFF_S = OFF_AO + XN_BYTES;
static constexpr size_t S_BYTES_1 = (size_t)NSP * NSP * 2;          // 32 MB / batch

__device__ __forceinline__ void gld16(void* lds, const void* g) {
  __builtin_amdgcn_global_load_lds(
      (__attribute__((address_space(1))) void*)(g),
      (__attribute__((address_space(3))) void*)(lds),
      16, 0, 0);
}

// ---------------- zero scratch ----------------
__global__ void zero4(floatx4* p, long n4) {
  long i = (long)blockIdx.x * 256 + threadIdx.x;
  if (i < n4) p[i] = floatx4{0.f, 0.f, 0.f, 0.f};
}

// ---------------- GroupNorm ----------------
__global__ __launch_bounds__(256) void gn_stats(const float* __restrict__ x,
                                                float* __restrict__ st) {
  int b = blockIdx.y;
  int tid = (int)threadIdx.x;
  int c0 = (tid * 4) & (CH - 1);
  int g = c0 >> 4;
  const float* base = x + (long)b * NSP * CH + (long)blockIdx.x * 16 * CH + tid * 4;
  float s = 0.f, s2 = 0.f;
#pragma unroll
  for (int it = 0; it < 8; ++it) {
    floatx4 v = *(const floatx4*)(base + (long)it * 1024);
#pragma unroll
    for (int r = 0; r < 4; ++r) { s += v[r]; s2 += v[r] * v[r]; }
  }
  __shared__ float gs[32], gs2[32];
  if (tid < 32) { gs[tid] = 0.f; gs2[tid] = 0.f; }
  __syncthreads();
  atomicAdd(&gs[g], s);
  atomicAdd(&gs2[g], s2);
  __syncthreads();
  if (tid < 32) {
    atomicAdd(&st[(b * 32 + tid) * 2], gs[tid]);
    atomicAdd(&st[(b * 32 + tid) * 2 + 1], gs2[tid]);
  }
}

__global__ void gn_finalize(float* st) {
  int bg = threadIdx.x;  // 64
  float s = st[bg * 2], s2 = st[bg * 2 + 1];
  const float inv = 1.f / 65536.f;
  float mean = s * inv;
  float var = s2 * inv - mean * mean;
  st[bg * 2] = mean;
  st[bg * 2 + 1] = rsqrtf(var + 1e-5f);
}

__global__ __launch_bounds__(256) void gn_apply(const float* __restrict__ x,
                                                const float* __restrict__ st,
                                                const float* __restrict__ gamma,
                                                const float* __restrict__ beta,
                                                half_t* __restrict__ xn) {
  long i = ((long)blockIdx.x * 256 + threadIdx.x) * 8;
  int c = (int)(i & (CH - 1));
  int b = (int)(i >> 21);
  int g = c >> 4;
  float mean = st[((b << 5) + g) * 2];
  float rstd = st[((b << 5) + g) * 2 + 1];
  floatx4 a = *(const floatx4*)(x + i);
  floatx4 d = *(const floatx4*)(x + i + 4);
  half8 o;
#pragma unroll
  for (int r = 0; r < 4; ++r) {
    o[r]     = (half_t)((a[r] - mean) * rstd * gamma[c + r] + beta[c + r]);
    o[r + 4] = (half_t)((d[r] - mean) * rstd * gamma[c + r + 4] + beta[c + r + 4]);
  }
  *(half8*)(xn + i) = o;
}

// ---------------- transposes ----------------
__global__ __launch_bounds__(256) void transpose_w(
    const float* __restrict__ w0, const float* __restrict__ w1,
    const float* __restrict__ w2, const float* __restrict__ w3,
    half_t* __restrict__ o0, half_t* __restrict__ o1,
    half_t* __restrict__ o2, half_t* __restrict__ o3) {
  const float* w; half_t* o;
  switch (blockIdx.z) {
    case 0: w = w0; o = o0; break;
    case 1: w = w1; o = o1; break;
    case 2: w = w2; o = o2; break;
    default: w = w3; o = o3; break;
  }
  __shared__ float t[32][33];
  int d0 = blockIdx.x * 32, c0 = blockIdx.y * 32;
  int tx = threadIdx.x & 31, ty = threadIdx.x >> 5;
#pragma unroll
  for (int i = 0; i < 4; ++i)
    t[ty + i * 8][tx] = w[(long)(c0 + ty + i * 8) * CH + d0 + tx];
  __syncthreads();
#pragma unroll
  for (int i = 0; i < 4; ++i) {
    int d = ty + i * 8;
    o[(long)(d0 + d) * CH + c0 + tx] = (half_t)t[tx][d];
  }
}

// v strided inside qkv buffer: ld = NQKV
__global__ __launch_bounds__(256) void transpose_v(const half_t* __restrict__ v,
                                                   half_t* __restrict__ vt) {
  __shared__ half_t t[32][33];
  int b = blockIdx.z;
  int d0 = blockIdx.x * 32, n0 = blockIdx.y * 32;
  int tx = threadIdx.x & 31, ty = threadIdx.x >> 5;
  const half_t* vb = v + (long)b * NSP * NQKV;
  half_t* ob = vt + (long)b * NSP * CH;
#pragma unroll
  for (int i = 0; i < 4; ++i)
    t[ty + i * 8][tx] = vb[(long)(n0 + ty + i * 8) * NQKV + d0 + tx];
  __syncthreads();
#pragma unroll
  for (int i = 0; i < 4; ++i) {
    int d = ty + i * 8;
    ob[(long)(d0 + d) * NSP + n0 + tx] = t[tx][d];
  }
}

// ---------------- NT GEMM: C[M,N] = X[M,K] * Y[N,K]^T ----------------
// Double-buffered LDS, ONE barrier per K-iter:
//   prologue: stage buf0
//   iter: barrier (own vmcnt drained -> cur ready; all waves done reading nxt)
//         -> issue next stage into nxt -> compute cur -> swap
// Staging source addresses hoisted as int32 byte-offsets from Xb (all
// operands live inside one ws allocation, diffs < 2^31).
// LDS chunk swizzle: 16B chunk c of row r at slot c ^ (r & (CPR-1)) (CPR=8:
// conflict-free, measured 0). SWZ=1: XCD block remap, window of 256.
// EPI: 1 = fused QKV: bias select {b0,b1,b2} by n-range, n<512 scaled; half
//      2 = +bias(b0) +resid, float store
//      3 = scores: store exp(acc) half + atomicAdd per-row sums into rowsum
//      4 = PV: scale by 1/rowsum[row], half store
template <int BM, int BN, int BK, int EPI, int SWZ, typename OutT>
__global__ __launch_bounds__(256) void gemm_nt(
    const half_t* __restrict__ X, const half_t* __restrict__ Y,
    OutT* __restrict__ Co, const float* __restrict__ b0,
    const float* __restrict__ b1, const float* __restrict__ b2,
    const float* __restrict__ resid, float* __restrict__ rowsum,
    int M, int N, int K, int ldx, int ldy, int ldc,
    long xbs, long ybs, long cbs, float scale) {
  constexpr int SM = BM / 32;       // m-subtiles per wave (2x2 wave grid)
  constexpr int SN = BN / 32;
  constexpr int ROWS = BM + BN;
  constexpr int CPR = BK / 8;       // 16B chunks per row
  constexpr int RPW = 64 / CPR;     // rows staged per wave per round
  constexpr int ROUNDS = (ROWS * BK * 2) / 4096;
  constexpr int KSTEPS = BK / 32;
  constexpr int BUF = ROWS * BK;    // halfs per buffer
  static_assert(BM % (4 * RPW) == 0, "no As/Bs straddle within a round");
  static_assert(CPR == 8, "CPR=8 is the conflict-free LDS config");
  __shared__ __align__(16) half_t Sh[2 * BUF];

  const int zb = blockIdx.z;
  int bx, by;
  if (SWZ) {
    int lin = (int)(blockIdx.x + gridDim.x * blockIdx.y);
    int wmt = 256 / (int)gridDim.x;  // m-tiles per 256-block window
    by = wmt * (lin >> 8) + ((lin & 255) % wmt);
    bx = (lin & 255) / wmt;
  } else {
    bx = blockIdx.x;
    by = blockIdx.y;
  }

  const half_t* Xb = X + (long)zb * xbs;
  const half_t* Yb = Y + (long)zb * ybs;
  OutT* Cb = Co + (long)zb * cbs;

  const int m0 = by * BM;
  const int n0 = bx * BN;
  const int tid = (int)threadIdx.x;
  const int wave = tid >> 6;
  const int lane = tid & 63;
  const int quad = lane >> 4;
  const int l16 = lane & 15;
  const int wm = wave >> 1;
  const int wn = wave & 1;

  floatx4 acc[SM][SN] = {};

  const int srow = lane / CPR;
  const int schunk = lane % CPR;
  const char* Xc = (const char*)Xb;

  // hoisted staging byte-offsets (per lane, per round), relative to Xb
  int soff[ROUNDS];
#pragma unroll
  for (int r = 0; r < ROUNDS; ++r) {
    int row = r * (4 * RPW) + wave * RPW + srow;
    int gchunk = schunk ^ (row & (CPR - 1));
    const char* p = (row < BM)
        ? (const char*)(Xb + (long)(m0 + row) * ldx)
        : (const char*)(Yb + (long)(n0 + row - BM) * ldy);
    soff[r] = (int)(p + gchunk * 16 - Xc);
  }

  half_t* cur = Sh;
  half_t* nxt = Sh + BUF;
  // prologue: stage k0 = 0
#pragma unroll
  for (int r = 0; r < ROUNDS; ++r)
    gld16((char*)cur + (r * 4 + wave) * 1024, Xc + (long)soff[r]);

  for (int k0 = 0; k0 < K; k0 += BK) {
    __syncthreads();  // cur staged & visible; nxt free for overwrite
    if (k0 + BK < K) {
#pragma unroll
      for (int r = 0; r < ROUNDS; ++r) {
        soff[r] += BK * 2;
        gld16((char*)nxt + (r * 4 + wave) * 1024, Xc + (long)soff[r]);
      }
    }
    half_t* As = cur;
    half_t* Bs = cur + BM * BK;
#pragma unroll
    for (int kk = 0; kk < KSTEPS; ++kk) {
      half8 af[SM], bf[SN];
#pragma unroll
      for (int i = 0; i < SM; ++i) {
        int m = wm * (BM / 2) + i * 16 + l16;
        int cc = (kk * 4 + quad) ^ (m & (CPR - 1));
        af[i] = *(const half8*)(As + m * BK + cc * 8);
      }
#pragma unroll
      for (int j = 0; j < SN; ++j) {
        int n = wn * (BN / 2) + j * 16 + l16;
        int cc = (kk * 4 + quad) ^ (n & (CPR - 1));
        bf[j] = *(const half8*)(Bs + n * BK + cc * 8);
      }
#pragma unroll
      for (int i = 0; i < SM; ++i)
#pragma unroll
        for (int j = 0; j < SN; ++j)
          acc[i][j] = __builtin_amdgcn_mfma_f32_16x16x32_f16(af[i], bf[j], acc[i][j], 0, 0, 0);
    }
    half_t* t = cur; cur = nxt; nxt = t;
  }

#pragma unroll
  for (int i = 0; i < SM; ++i) {
    int gmb = m0 + wm * (BM / 2) + i * 16 + quad * 4;
    float rs[4] = {0.f, 0.f, 0.f, 0.f};
    float inv[4];
    if (EPI == 4) {
#pragma unroll
      for (int r = 0; r < 4; ++r)
        inv[r] = 1.f / rowsum[(long)zb * NSP + gmb + r];
    }
#pragma unroll
    for (int j = 0; j < SN; ++j) {
      int gn = n0 + wn * (BN / 2) + j * 16 + l16;
      float bias = 0.f, sc = 1.f;
      if (EPI == 1) {
        if (gn < CH) { bias = b0[gn]; sc = scale; }
        else if (gn < 2 * CH) { bias = b1[gn - CH]; }
        else { bias = b2[gn - 2 * CH]; }
      } else if (EPI == 2) {
        bias = b0[gn];
      }
#pragma unroll
      for (int r = 0; r < 4; ++r) {
        long idx = (long)(gmb + r) * ldc + gn;
        float v = acc[i][j][r];
        if (EPI == 1) v = (v + bias) * sc;
        if (EPI == 2) v = v + bias + resid[idx];
        if (EPI == 3) { v = __expf(v); rs[r] += v; }
        if (EPI == 4) v *= inv[r];
        Cb[idx] = (OutT)v;
      }
    }
    if (EPI == 3) {
#pragma unroll
      for (int r = 0; r < 4; ++r) {
        float v = rs[r];
        v += __shfl_xor(v, 1);
        v += __shfl_xor(v, 2);
        v += __shfl_xor(v, 4);
        v += __shfl_xor(v, 8);
        if (l16 == 0) atomicAdd(&rowsum[(long)zb * NSP + gmb + r], v);
      }
    }
  }
}

extern "C" void kernel_launch(void* const* d_in, const int* in_sizes, int n_in,
                              void* d_out, int out_size, void* d_ws, size_t ws_size,
                              hipStream_t stream) {
  const float* x = (const float*)d_in[0];
  const float* gamma = (const float*)d_in[1];
  const float* beta = (const float*)d_in[2];
  const float* wq = (const float*)d_in[3];
  const float* bq = (const float*)d_in[4];
  const float* wk = (const float*)d_in[5];
  const float* bk = (const float*)d_in[6];
  const float* wv = (const float*)d_in[7];
  const float* bv = (const float*)d_in[8];
  const float* wp = (const float*)d_in[9];
  const float* bp = (const float*)d_in[10];
  float* out = (float*)d_out;
  char* ws = (char*)d_ws;

  float* st = (float*)(ws + OFF_STATS);
  float* rsum = (float*)(ws + OFF_ROWSUM);   // [BATCH][NSP]
  half_t* wqkvT = (half_t*)(ws + OFF_WQKV);  // [1536][512]
  half_t* wpT = (half_t*)(ws + OFF_WP);
  half_t* xn = (half_t*)(ws + OFF_XN);
  half_t* qkv = (half_t*)(ws + OFF_QKV);     // [B*4096][1536]
  half_t* vt = (half_t*)(ws + OFF_VT);
  half_t* ao = (half_t*)(ws + OFF_AO);
  half_t* S = (half_t*)(ws + OFF_S);

  half_t* q = qkv;            // ld NQKV
  half_t* k = qkv + CH;       // ld NQKV
  half_t* v = qkv + 2 * CH;   // ld NQKV

  const float scale = 0.044194173824159216f;  // 1/sqrt(512)
  const long bQKV = (long)NSP * NQKV;
  const long bNC = (long)NSP * CH;
  const long bNN = (long)NSP * NSP;

  // zero stats + rowsum (33280 B = 2080 float4)
  zero4<<<9, 256, 0, stream>>>((floatx4*)st, 2080);
  gn_stats<<<dim3(256, BATCH), 256, 0, stream>>>(x, st);
  gn_finalize<<<1, 64, 0, stream>>>(st);
  gn_apply<<<2048, 256, 0, stream>>>(x, st, gamma, beta, xn);
  transpose_w<<<dim3(16, 16, 4), 256, 0, stream>>>(
      wq, wk, wv, wp, wqkvT, wqkvT + (size_t)CH * CH, wqkvT + 2 * (size_t)CH * CH, wpT);

  // fused qkv = xn @ [wq|wk|wv]^T + bias (q scaled): 128x64 dbuf, (24,64)
  gemm_nt<128, 64, 64, 1, 0, half_t><<<dim3(NQKV / 64, BATCH * NSP / 128, 1), 256, 0, stream>>>(
      xn, wqkvT, qkv, bq, bk, bv, nullptr, nullptr, BATCH * NSP, NQKV, CH,
      CH, CH, NQKV, 0, 0, 0, scale);
  transpose_v<<<dim3(16, 128, BATCH), 256, 0, stream>>>(v, vt);

  bool full = ws_size >= OFF_S + 2 * S_BYTES_1;
  if (full) {
    // scores -> exp(s) + row sums: 128x64 dbuf + XCD swizzle, (64,32,2)
    gemm_nt<128, 64, 64, 3, 1, half_t><<<dim3(NSP / 64, NSP / 128, BATCH), 256, 0, stream>>>(
        q, k, S, nullptr, nullptr, nullptr, nullptr, rsum, NSP, NSP, CH,
        NQKV, NQKV, NSP, bQKV, bQKV, bNN, 1.f);
    // PV: 64x64 dbuf + XCD swizzle, (8,64,2)
    gemm_nt<64, 64, 64, 4, 1, half_t><<<dim3(CH / 64, NSP / 64, BATCH), 256, 0, stream>>>(
        S, vt, ao, nullptr, nullptr, nullptr, nullptr, rsum, NSP, CH, NSP,
        NSP, NSP, CH, bNN, bNC, bNC, 1.f);
  } else {
    for (int bb = 0; bb < BATCH; ++bb) {
      gemm_nt<128, 64, 64, 3, 1, half_t><<<dim3(NSP / 64, NSP / 128, 1), 256, 0, stream>>>(
          q + bb * bQKV, k + bb * bQKV, S, nullptr, nullptr, nullptr, nullptr,
          rsum + bb * NSP, NSP, NSP, CH, NQKV, NQKV, NSP, 0, 0, 0, 1.f);
      gemm_nt<64, 64, 64, 4, 1, half_t><<<dim3(CH / 64, NSP / 64, 1), 256, 0, stream>>>(
          S, vt + bb * bNC, ao + bb * bNC, nullptr, nullptr, nullptr, nullptr,
          rsum + bb * NSP, NSP, CH, NSP, NSP, NSP, CH, 0, 0, 0, 1.f);
    }
  }
  // out = ao @ wp^T + bp + x : 64x64 dbuf, (8,128)
  gemm_nt<64, 64, 64, 2, 0, float><<<dim3(CH / 64, BATCH * NSP / 64, 1), 256, 0, stream>>>(
      ao, wpT, out, bp, nullptr, nullptr, x, nullptr, BATCH * NSP, CH, CH,
      CH, CH, CH, 0, 0, 0, 1.f);
}

// Round 8
// 276.286 us; speedup vs baseline: 1.1465x; 1.1465x over previous
//
#include <hip/hip_runtime.h>
#include <hip/hip_fp16.h>

typedef _Float16 half_t;
typedef _Float16 half8 __attribute__((ext_vector_type(8)));
typedef float floatx4 __attribute__((ext_vector_type(4)));

static constexpr int BATCH = 2;
static constexpr int NSP = 4096;   // H*W
static constexpr int CH = 512;
static constexpr int NQKV = 3 * CH;  // 1536

// ---- ws layout (bytes) ----
static constexpr size_t OFF_STATS = 0;                              // 128 floats
static constexpr size_t OFF_ROWSUM = 512;                           // B*NSP floats (32 KB)
static constexpr size_t OFF_WQKV = 36864;
static constexpr size_t WQKV_BYTES = (size_t)NQKV * CH * 2;         // 1.5 MB
static constexpr size_t OFF_WP = OFF_WQKV + WQKV_BYTES;
static constexpr size_t WP_BYTES = (size_t)CH * CH * 2;             // 0.5 MB
static constexpr size_t OFF_XN = OFF_WP + WP_BYTES;
static constexpr size_t XN_BYTES = (size_t)BATCH * NSP * CH * 2;    // 8 MB
static constexpr size_t OFF_QKV = OFF_XN + XN_BYTES;
static constexpr size_t QKV_BYTES = (size_t)BATCH * NSP * NQKV * 2; // 24 MB
static constexpr size_t OFF_VT = OFF_QKV + QKV_BYTES;
static constexpr size_t OFF_AO = OFF_VT + XN_BYTES;
static constexpr size_t OFF_S = OFF_AO + XN_BYTES;
static constexpr size_t S_BYTES_1 = (size_t)NSP * NSP * 2;          // 32 MB / batch

__device__ __forceinline__ void gld16(void* lds, const void* g) {
  __builtin_amdgcn_global_load_lds(
      (__attribute__((address_space(1))) void*)(g),
      (__attribute__((address_space(3))) void*)(lds),
      16, 0, 0);
}

// ---------------- zero scratch ----------------
__global__ void zero4(floatx4* p, long n4) {
  long i = (long)blockIdx.x * 256 + threadIdx.x;
  if (i < n4) p[i] = floatx4{0.f, 0.f, 0.f, 0.f};
}

// ---------------- GroupNorm ----------------
__global__ __launch_bounds__(256) void gn_stats(const float* __restrict__ x,
                                                float* __restrict__ st) {
  int b = blockIdx.y;
  int tid = (int)threadIdx.x;
  int c0 = (tid * 4) & (CH - 1);
  int g = c0 >> 4;
  const float* base = x + (long)b * NSP * CH + (long)blockIdx.x * 16 * CH + tid * 4;
  float s = 0.f, s2 = 0.f;
#pragma unroll
  for (int it = 0; it < 8; ++it) {
    floatx4 v = *(const floatx4*)(base + (long)it * 1024);
#pragma unroll
    for (int r = 0; r < 4; ++r) { s += v[r]; s2 += v[r] * v[r]; }
  }
  __shared__ float gs[32], gs2[32];
  if (tid < 32) { gs[tid] = 0.f; gs2[tid] = 0.f; }
  __syncthreads();
  atomicAdd(&gs[g], s);
  atomicAdd(&gs2[g], s2);
  __syncthreads();
  if (tid < 32) {
    atomicAdd(&st[(b * 32 + tid) * 2], gs[tid]);
    atomicAdd(&st[(b * 32 + tid) * 2 + 1], gs2[tid]);
  }
}

__global__ void gn_finalize(float* st) {
  int bg = threadIdx.x;  // 64
  float s = st[bg * 2], s2 = st[bg * 2 + 1];
  const float inv = 1.f / 65536.f;
  float mean = s * inv;
  float var = s2 * inv - mean * mean;
  st[bg * 2] = mean;
  st[bg * 2 + 1] = rsqrtf(var + 1e-5f);
}

__global__ __launch_bounds__(256) void gn_apply(const float* __restrict__ x,
                                                const float* __restrict__ st,
                                                const float* __restrict__ gamma,
                                                const float* __restrict__ beta,
                                                half_t* __restrict__ xn) {
  long i = ((long)blockIdx.x * 256 + threadIdx.x) * 8;
  int c = (int)(i & (CH - 1));
  int b = (int)(i >> 21);
  int g = c >> 4;
  float mean = st[((b << 5) + g) * 2];
  float rstd = st[((b << 5) + g) * 2 + 1];
  floatx4 a = *(const floatx4*)(x + i);
  floatx4 d = *(const floatx4*)(x + i + 4);
  half8 o;
#pragma unroll
  for (int r = 0; r < 4; ++r) {
    o[r]     = (half_t)((a[r] - mean) * rstd * gamma[c + r] + beta[c + r]);
    o[r + 4] = (half_t)((d[r] - mean) * rstd * gamma[c + r + 4] + beta[c + r + 4]);
  }
  *(half8*)(xn + i) = o;
}

// ---------------- transposes ----------------
__global__ __launch_bounds__(256) void transpose_w(
    const float* __restrict__ w0, const float* __restrict__ w1,
    const float* __restrict__ w2, const float* __restrict__ w3,
    half_t* __restrict__ o0, half_t* __restrict__ o1,
    half_t* __restrict__ o2, half_t* __restrict__ o3) {
  const float* w; half_t* o;
  switch (blockIdx.z) {
    case 0: w = w0; o = o0; break;
    case 1: w = w1; o = o1; break;
    case 2: w = w2; o = o2; break;
    default: w = w3; o = o3; break;
  }
  __shared__ float t[32][33];
  int d0 = blockIdx.x * 32, c0 = blockIdx.y * 32;
  int tx = threadIdx.x & 31, ty = threadIdx.x >> 5;
#pragma unroll
  for (int i = 0; i < 4; ++i)
    t[ty + i * 8][tx] = w[(long)(c0 + ty + i * 8) * CH + d0 + tx];
  __syncthreads();
#pragma unroll
  for (int i = 0; i < 4; ++i) {
    int d = ty + i * 8;
    o[(long)(d0 + d) * CH + c0 + tx] = (half_t)t[tx][d];
  }
}

// v strided inside qkv buffer: ld = NQKV
__global__ __launch_bounds__(256) void transpose_v(const half_t* __restrict__ v,
                                                   half_t* __restrict__ vt) {
  __shared__ half_t t[32][33];
  int b = blockIdx.z;
  int d0 = blockIdx.x * 32, n0 = blockIdx.y * 32;
  int tx = threadIdx.x & 31, ty = threadIdx.x >> 5;
  const half_t* vb = v + (long)b * NSP * NQKV;
  half_t* ob = vt + (long)b * NSP * CH;
#pragma unroll
  for (int i = 0; i < 4; ++i)
    t[ty + i * 8][tx] = vb[(long)(n0 + ty + i * 8) * NQKV + d0 + tx];
  __syncthreads();
#pragma unroll
  for (int i = 0; i < 4; ++i) {
    int d = ty + i * 8;
    ob[(long)(d0 + d) * NSP + n0 + tx] = t[tx][d];
  }
}

// ---------------- NT GEMM: C[M,N] = X[M,K] * Y[N,K]^T ----------------
// R6 structure (single LDS buffer, 2 barriers/iter) + hoisted addresses:
//  - staging: per-round int32 byte-offset from Xb, += BK*2 per iter
//  - fragments: chunk index (kk*4+quad)^(row&(CPR-1)) factors as
//    (quad^(row&..)) ^ (kk<<2); kk-dependence is byte-XOR (kk<<6) below the
//    row-stride bit -> precompute kk=0 offsets, in-loop 1 XOR per read.
// LDS chunk swizzle on global side (global_load_lds forces lane->slot);
// measured 0 bank conflicts. SWZ=1: XCD block remap (window 256).
// EPI: 1 = fused QKV: bias select {b0,b1,b2} by n-range, n<512 scaled; half
//      2 = +bias(b0) +resid, float store
//      3 = scores: store exp(acc) half + atomicAdd per-row sums into rowsum
//      4 = PV: scale by 1/rowsum[row], half store
template <int BM, int BN, int BK, int EPI, int SWZ, typename OutT>
__global__ __launch_bounds__(256) void gemm_nt(
    const half_t* __restrict__ X, const half_t* __restrict__ Y,
    OutT* __restrict__ Co, const float* __restrict__ b0,
    const float* __restrict__ b1, const float* __restrict__ b2,
    const float* __restrict__ resid, float* __restrict__ rowsum,
    int M, int N, int K, int ldx, int ldy, int ldc,
    long xbs, long ybs, long cbs, float scale) {
  constexpr int SM = BM / 32;       // m-subtiles per wave (2x2 wave grid)
  constexpr int SN = BN / 32;
  constexpr int ROWS = BM + BN;
  constexpr int CPR = BK / 8;       // 16B chunks per row
  constexpr int RPW = 64 / CPR;     // rows staged per wave per round
  constexpr int ROUNDS = (ROWS * BK * 2) / 4096;
  constexpr int KSTEPS = BK / 32;
  static_assert(BM % (4 * RPW) == 0, "no As/Bs straddle within a round");
  __shared__ __align__(16) half_t Sh[ROWS * BK];

  const int zb = blockIdx.z;
  int bx, by;
  if (SWZ) {
    int lin = (int)(blockIdx.x + gridDim.x * blockIdx.y);
    int wmt = 256 / (int)gridDim.x;  // m-tiles per 256-block window
    by = wmt * (lin >> 8) + ((lin & 255) % wmt);
    bx = (lin & 255) / wmt;
  } else {
    bx = blockIdx.x;
    by = blockIdx.y;
  }

  const half_t* Xb = X + (long)zb * xbs;
  const half_t* Yb = Y + (long)zb * ybs;
  OutT* Cb = Co + (long)zb * cbs;

  const int m0 = by * BM;
  const int n0 = bx * BN;
  const int tid = (int)threadIdx.x;
  const int wave = tid >> 6;
  const int lane = tid & 63;
  const int quad = lane >> 4;
  const int l16 = lane & 15;
  const int wm = wave >> 1;
  const int wn = wave & 1;

  floatx4 acc[SM][SN] = {};

  const int srow = lane / CPR;
  const int schunk = lane % CPR;
  const char* Xc = (const char*)Xb;

  // hoisted staging byte-offsets (per lane, per round), relative to Xb;
  // all operands live in one ws allocation -> diffs fit int32 (signed ok)
  int soff[ROUNDS];
#pragma unroll
  for (int r = 0; r < ROUNDS; ++r) {
    int row = r * (4 * RPW) + wave * RPW + srow;
    int gchunk = schunk ^ (row & (CPR - 1));
    const char* p = (row < BM)
        ? (const char*)(Xb + (long)(m0 + row) * ldx)
        : (const char*)(Yb + (long)(n0 + row - BM) * ldy);
    soff[r] = (int)(p + gchunk * 16 - Xc);
  }

  // hoisted fragment LDS byte offsets at kk=0 (relative to Sh)
  int offA[SM], offB[SN];
#pragma unroll
  for (int i = 0; i < SM; ++i) {
    int m = wm * (BM / 2) + i * 16 + l16;
    int cc = quad ^ (m & (CPR - 1));
    offA[i] = (m * BK + cc * 8) * 2;
  }
#pragma unroll
  for (int j = 0; j < SN; ++j) {
    int n = wn * (BN / 2) + j * 16 + l16;
    int cc = quad ^ (n & (CPR - 1));
    offB[j] = (BM * BK + n * BK + cc * 8) * 2;
  }

  for (int k0 = 0; k0 < K; k0 += BK) {
#pragma unroll
    for (int r = 0; r < ROUNDS; ++r) {
      gld16((char*)Sh + (r * 4 + wave) * 1024, Xc + (long)soff[r]);
      soff[r] += BK * 2;
    }
    __syncthreads();  // drains vmcnt(0): staging visible

#pragma unroll
    for (int kk = 0; kk < KSTEPS; ++kk) {
      const int kx = kk << 6;  // byte-XOR key for chunk swizzle
      half8 af[SM], bf[SN];
#pragma unroll
      for (int i = 0; i < SM; ++i)
        af[i] = *(const half8*)((const char*)Sh + (offA[i] ^ kx));
#pragma unroll
      for (int j = 0; j < SN; ++j)
        bf[j] = *(const half8*)((const char*)Sh + (offB[j] ^ kx));
#pragma unroll
      for (int i = 0; i < SM; ++i)
#pragma unroll
        for (int j = 0; j < SN; ++j)
          acc[i][j] = __builtin_amdgcn_mfma_f32_16x16x32_f16(af[i], bf[j], acc[i][j], 0, 0, 0);
    }
    __syncthreads();
  }

#pragma unroll
  for (int i = 0; i < SM; ++i) {
    int gmb = m0 + wm * (BM / 2) + i * 16 + quad * 4;
    float rs[4] = {0.f, 0.f, 0.f, 0.f};
    float inv[4];
    if (EPI == 4) {
#pragma unroll
      for (int r = 0; r < 4; ++r)
        inv[r] = 1.f / rowsum[(long)zb * NSP + gmb + r];
    }
#pragma unroll
    for (int j = 0; j < SN; ++j) {
      int gn = n0 + wn * (BN / 2) + j * 16 + l16;
      float bias = 0.f, sc = 1.f;
      if (EPI == 1) {
        if (gn < CH) { bias = b0[gn]; sc = scale; }
        else if (gn < 2 * CH) { bias = b1[gn - CH]; }
        else { bias = b2[gn - 2 * CH]; }
      } else if (EPI == 2) {
        bias = b0[gn];
      }
#pragma unroll
      for (int r = 0; r < 4; ++r) {
        long idx = (long)(gmb + r) * ldc + gn;
        float v = acc[i][j][r];
        if (EPI == 1) v = (v + bias) * sc;
        if (EPI == 2) v = v + bias + resid[idx];
        if (EPI == 3) { v = __expf(v); rs[r] += v; }
        if (EPI == 4) v *= inv[r];
        Cb[idx] = (OutT)v;
      }
    }
    if (EPI == 3) {
#pragma unroll
      for (int r = 0; r < 4; ++r) {
        float v = rs[r];
        v += __shfl_xor(v, 1);
        v += __shfl_xor(v, 2);
        v += __shfl_xor(v, 4);
        v += __shfl_xor(v, 8);
        if (l16 == 0) atomicAdd(&rowsum[(long)zb * NSP + gmb + r], v);
      }
    }
  }
}

extern "C" void kernel_launch(void* const* d_in, const int* in_sizes, int n_in,
                              void* d_out, int out_size, void* d_ws, size_t ws_size,
                              hipStream_t stream) {
  const float* x = (const float*)d_in[0];
  const float* gamma = (const float*)d_in[1];
  const float* beta = (const float*)d_in[2];
  const float* wq = (const float*)d_in[3];
  const float* bq = (const float*)d_in[4];
  const float* wk = (const float*)d_in[5];
  const float* bk = (const float*)d_in[6];
  const float* wv = (const float*)d_in[7];
  const float* bv = (const float*)d_in[8];
  const float* wp = (const float*)d_in[9];
  const float* bp = (const float*)d_in[10];
  float* out = (float*)d_out;
  char* ws = (char*)d_ws;

  float* st = (float*)(ws + OFF_STATS);
  float* rsum = (float*)(ws + OFF_ROWSUM);   // [BATCH][NSP]
  half_t* wqkvT = (half_t*)(ws + OFF_WQKV);  // [1536][512]
  half_t* wpT = (half_t*)(ws + OFF_WP);
  half_t* xn = (half_t*)(ws + OFF_XN);
  half_t* qkv = (half_t*)(ws + OFF_QKV);     // [B*4096][1536]
  half_t* vt = (half_t*)(ws + OFF_VT);
  half_t* ao = (half_t*)(ws + OFF_AO);
  half_t* S = (half_t*)(ws + OFF_S);

  half_t* q = qkv;            // ld NQKV
  half_t* k = qkv + CH;       // ld NQKV
  half_t* v = qkv + 2 * CH;   // ld NQKV

  const float scale = 0.044194173824159216f;  // 1/sqrt(512)
  const long bQKV = (long)NSP * NQKV;
  const long bNC = (long)NSP * CH;
  const long bNN = (long)NSP * NSP;

  // zero stats + rowsum (33280 B = 2080 float4)
  zero4<<<9, 256, 0, stream>>>((floatx4*)st, 2080);
  gn_stats<<<dim3(256, BATCH), 256, 0, stream>>>(x, st);
  gn_finalize<<<1, 64, 0, stream>>>(st);
  gn_apply<<<2048, 256, 0, stream>>>(x, st, gamma, beta, xn);
  transpose_w<<<dim3(16, 16, 4), 256, 0, stream>>>(
      wq, wk, wv, wp, wqkvT, wqkvT + (size_t)CH * CH, wqkvT + 2 * (size_t)CH * CH, wpT);

  // fused qkv = xn @ [wq|wk|wv]^T + bias (q scaled): 128x128 BK=64, (12,64)
  gemm_nt<128, 128, 64, 1, 0, half_t><<<dim3(NQKV / 128, BATCH * NSP / 128, 1), 256, 0, stream>>>(
      xn, wqkvT, qkv, bq, bk, bv, nullptr, nullptr, BATCH * NSP, NQKV, CH,
      CH, CH, NQKV, 0, 0, 0, scale);
  transpose_v<<<dim3(16, 128, BATCH), 256, 0, stream>>>(v, vt);

  bool full = ws_size >= OFF_S + 2 * S_BYTES_1;
  if (full) {
    // scores -> exp(s) + row sums: 128x128 BK=64 + XCD swizzle, (32,32,2)
    gemm_nt<128, 128, 64, 3, 1, half_t><<<dim3(32, 32, BATCH), 256, 0, stream>>>(
        q, k, S, nullptr, nullptr, nullptr, nullptr, rsum, NSP, NSP, CH,
        NQKV, NQKV, NSP, bQKV, bQKV, bNN, 1.f);
    // PV: 64x64 BK=128 + XCD swizzle, (8,64,2)
    gemm_nt<64, 64, 128, 4, 1, half_t><<<dim3(CH / 64, NSP / 64, BATCH), 256, 0, stream>>>(
        S, vt, ao, nullptr, nullptr, nullptr, nullptr, rsum, NSP, CH, NSP,
        NSP, NSP, CH, bNN, bNC, bNC, 1.f);
  } else {
    for (int bb = 0; bb < BATCH; ++bb) {
      gemm_nt<128, 128, 64, 3, 1, half_t><<<dim3(32, 32, 1), 256, 0, stream>>>(
          q + bb * bQKV, k + bb * bQKV, S, nullptr, nullptr, nullptr, nullptr,
          rsum + bb * NSP, NSP, NSP, CH, NQKV, NQKV, NSP, 0, 0, 0, 1.f);
      gemm_nt<64, 64, 128, 4, 1, half_t><<<dim3(CH / 64, NSP / 64, 1), 256, 0, stream>>>(
          S, vt + bb * bNC, ao + bb * bNC, nullptr, nullptr, nullptr, nullptr,
          rsum + bb * NSP, NSP, CH, NSP, NSP, NSP, CH, 0, 0, 0, 1.f);
    }
  }
  // out = ao @ wp^T + bp + x : 64x64 BK=128, (8,128)
  gemm_nt<64, 64, 128, 2, 0, float><<<dim3(CH / 64, BATCH * NSP / 64, 1), 256, 0, stream>>>(
      ao, wpT, out, bp, nullptr, nullptr, x, nullptr, BATCH * NSP, CH, CH,
      CH, CH, CH, 0, 0, 0, 1.f);
}

// Round 9
// 262.715 us; speedup vs baseline: 1.2057x; 1.0517x over previous
//
#include <hip/hip_runtime.h>
#include <hip/hip_fp16.h>

typedef _Float16 half_t;
typedef _Float16 half8 __attribute__((ext_vector_type(8)));
typedef float floatx4 __attribute__((ext_vector_type(4)));

static constexpr int BATCH = 2;
static constexpr int NSP = 4096;   // H*W
static constexpr int CH = 512;
static constexpr int NQKV = 3 * CH;  // 1536
static constexpr int KSPLIT = 4;

// ---- ws layout (bytes) ----
static constexpr size_t OFF_STATS = 0;                              // 128 floats
static constexpr size_t OFF_ROWSUM = 512;                           // B*NSP floats (32 KB)
static constexpr size_t OFF_PST = 33280;                            // GN partials: 2*256*32*2 f32 = 128 KB
static constexpr size_t OFF_WQKV = 196608;
static constexpr size_t WQKV_BYTES = (size_t)NQKV * CH * 2;         // 1.5 MB
static constexpr size_t OFF_WP = OFF_WQKV + WQKV_BYTES;
static constexpr size_t WP_BYTES = (size_t)CH * CH * 2;             // 0.5 MB
static constexpr size_t OFF_XN = OFF_WP + WP_BYTES;
static constexpr size_t XN_BYTES = (size_t)BATCH * NSP * CH * 2;    // 8 MB
static constexpr size_t OFF_QKV = OFF_XN + XN_BYTES;
static constexpr size_t QKV_BYTES = (size_t)BATCH * NSP * NQKV * 2; // 24 MB
static constexpr size_t OFF_VT = OFF_QKV + QKV_BYTES;
static constexpr size_t OFF_AO = OFF_VT + XN_BYTES;
static constexpr size_t OFF_S = OFF_AO + XN_BYTES;
static constexpr size_t S_BYTES_1 = (size_t)NSP * NSP * 2;          // 32 MB / batch
// PV split-K partials: 8 slabs x 4 MB = 32 MB, overlaying xn+qkv (dead by PV)
static constexpr size_t OFF_PART = OFF_XN;

__device__ __forceinline__ void gld16(void* lds, const void* g) {
  __builtin_amdgcn_global_load_lds(
      (__attribute__((address_space(1))) void*)(g),
      (__attribute__((address_space(3))) void*)(lds),
      16, 0, 0);
}

// ---------------- GroupNorm ----------------
// stage 1: 512 blocks write per-chunk group partials (no global atomics)
__global__ __launch_bounds__(256) void gn_stats(const float* __restrict__ x,
                                                float* __restrict__ pst) {
  int b = blockIdx.y;
  int tid = (int)threadIdx.x;
  int g = ((tid * 4) & (CH - 1)) >> 4;
  const float* base = x + (long)b * NSP * CH + (long)blockIdx.x * 16 * CH + tid * 4;
  float s = 0.f, s2 = 0.f;
#pragma unroll
  for (int it = 0; it < 8; ++it) {
    floatx4 v = *(const floatx4*)(base + (long)it * 1024);
#pragma unroll
    for (int r = 0; r < 4; ++r) { s += v[r]; s2 += v[r] * v[r]; }
  }
  __shared__ float gs[32], gs2[32];
  if (tid < 32) { gs[tid] = 0.f; gs2[tid] = 0.f; }
  __syncthreads();
  atomicAdd(&gs[g], s);
  atomicAdd(&gs2[g], s2);
  __syncthreads();
  if (tid < 32) {
    long idx = ((long)(b * 256 + blockIdx.x) * 32 + tid) * 2;
    pst[idx] = gs[tid];
    pst[idx + 1] = gs2[tid];
  }
}

// stage 2: reduce 256 chunks -> mean/rstd per (b,g); also zero rowsum
__global__ __launch_bounds__(256) void gn_finalize(const float* __restrict__ pst,
                                                   float* __restrict__ st,
                                                   float* __restrict__ rowsum) {
  int tid = (int)threadIdx.x;
  int bg = tid & 63;          // b*32+g? -> b = bg>>5, g = bg&31
  int p = tid >> 6;           // 4 chunk-subsets
  int b = bg >> 5, g = bg & 31;
  float s = 0.f, s2 = 0.f;
  for (int j = 0; j < 64; ++j) {
    int chunk = p * 64 + j;
    long idx = ((long)(b * 256 + chunk) * 32 + g) * 2;
    s += pst[idx];
    s2 += pst[idx + 1];
  }
  __shared__ float rs[64][4], rs2[64][4];
  rs[bg][p] = s;
  rs2[bg][p] = s2;
  __syncthreads();
  if (tid < 64) {
    float ts = rs[tid][0] + rs[tid][1] + rs[tid][2] + rs[tid][3];
    float ts2 = rs2[tid][0] + rs2[tid][1] + rs2[tid][2] + rs2[tid][3];
    const float inv = 1.f / 65536.f;
    float mean = ts * inv;
    float var = ts2 * inv - mean * mean;
    st[tid * 2] = mean;
    st[tid * 2 + 1] = rsqrtf(var + 1e-5f);
  }
  // zero rowsum (B*NSP = 8192 floats = 2048 float4)
  floatx4* rz = (floatx4*)rowsum;
#pragma unroll
  for (int j = 0; j < 8; ++j)
    rz[tid + j * 256] = floatx4{0.f, 0.f, 0.f, 0.f};
}

__global__ __launch_bounds__(256) void gn_apply(const float* __restrict__ x,
                                                const float* __restrict__ st,
                                                const float* __restrict__ gamma,
                                                const float* __restrict__ beta,
                                                half_t* __restrict__ xn) {
  long i = ((long)blockIdx.x * 256 + threadIdx.x) * 8;
  int c = (int)(i & (CH - 1));
  int b = (int)(i >> 21);
  int g = c >> 4;
  float mean = st[((b << 5) + g) * 2];
  float rstd = st[((b << 5) + g) * 2 + 1];
  floatx4 a = *(const floatx4*)(x + i);
  floatx4 d = *(const floatx4*)(x + i + 4);
  half8 o;
#pragma unroll
  for (int r = 0; r < 4; ++r) {
    o[r]     = (half_t)((a[r] - mean) * rstd * gamma[c + r] + beta[c + r]);
    o[r + 4] = (half_t)((d[r] - mean) * rstd * gamma[c + r + 4] + beta[c + r + 4]);
  }
  *(half8*)(xn + i) = o;
}

// ---------------- transposes ----------------
__global__ __launch_bounds__(256) void transpose_w(
    const float* __restrict__ w0, const float* __restrict__ w1,
    const float* __restrict__ w2, const float* __restrict__ w3,
    half_t* __restrict__ o0, half_t* __restrict__ o1,
    half_t* __restrict__ o2, half_t* __restrict__ o3) {
  const float* w; half_t* o;
  switch (blockIdx.z) {
    case 0: w = w0; o = o0; break;
    case 1: w = w1; o = o1; break;
    case 2: w = w2; o = o2; break;
    default: w = w3; o = o3; break;
  }
  __shared__ float t[32][33];
  int d0 = blockIdx.x * 32, c0 = blockIdx.y * 32;
  int tx = threadIdx.x & 31, ty = threadIdx.x >> 5;
#pragma unroll
  for (int i = 0; i < 4; ++i)
    t[ty + i * 8][tx] = w[(long)(c0 + ty + i * 8) * CH + d0 + tx];
  __syncthreads();
#pragma unroll
  for (int i = 0; i < 4; ++i) {
    int d = ty + i * 8;
    o[(long)(d0 + d) * CH + c0 + tx] = (half_t)t[tx][d];
  }
}

// v strided inside qkv buffer: ld = NQKV
__global__ __launch_bounds__(256) void transpose_v(const half_t* __restrict__ v,
                                                   half_t* __restrict__ vt) {
  __shared__ half_t t[32][33];
  int b = blockIdx.z;
  int d0 = blockIdx.x * 32, n0 = blockIdx.y * 32;
  int tx = threadIdx.x & 31, ty = threadIdx.x >> 5;
  const half_t* vb = v + (long)b * NSP * NQKV;
  half_t* ob = vt + (long)b * NSP * CH;
#pragma unroll
  for (int i = 0; i < 4; ++i)
    t[ty + i * 8][tx] = vb[(long)(n0 + ty + i * 8) * NQKV + d0 + tx];
  __syncthreads();
#pragma unroll
  for (int i = 0; i < 4; ++i) {
    int d = ty + i * 8;
    ob[(long)(d0 + d) * NSP + n0 + tx] = t[tx][d];
  }
}

// ---------------- NT GEMM: C[M,N] = X[M,K] * Y[N,K]^T ----------------
// R6 structure (single LDS buffer, 2 barriers/iter) + hoisted addresses.
// SWZ: 0 = none; 1 = window-256 XCD swizzle (scores); 2 = x/y swap so
//      blockIdx.x enumerates m-tiles -> A-panel sharers (same m, diff n)
//      are lin%8-equal -> same XCD -> A L2-served after first fetch.
// KSP: split-K count; blockIdx.z = b*KSP + ks; X/Y advance ks*K elements
//      (K = per-split length); C slab = blockIdx.z * cbs.
// EPI: 0 = plain half store (PV partials)
//      1 = fused QKV: bias select {b0,b1,b2} by n-range, n<512 scaled; half
//      2 = +bias(b0) +resid, float store
//      3 = scores: store exp(acc) half + atomicAdd per-row sums into rowsum
template <int BM, int BN, int BK, int EPI, int SWZ, int KSP, typename OutT>
__global__ __launch_bounds__(256) void gemm_nt(
    const half_t* __restrict__ X, const half_t* __restrict__ Y,
    OutT* __restrict__ Co, const float* __restrict__ b0,
    const float* __restrict__ b1, const float* __restrict__ b2,
    const float* __restrict__ resid, float* __restrict__ rowsum,
    int M, int N, int K, int ldx, int ldy, int ldc,
    long xbs, long ybs, long cbs, float scale) {
  constexpr int SM = BM / 32;       // m-subtiles per wave (2x2 wave grid)
  constexpr int SN = BN / 32;
  constexpr int ROWS = BM + BN;
  constexpr int CPR = BK / 8;       // 16B chunks per row
  constexpr int RPW = 64 / CPR;     // rows staged per wave per round
  constexpr int ROUNDS = (ROWS * BK * 2) / 4096;
  constexpr int KSTEPS = BK / 32;
  static_assert(BM % (4 * RPW) == 0, "no As/Bs straddle within a round");
  __shared__ __align__(16) half_t Sh[ROWS * BK];

  const int zb = blockIdx.z / KSP;
  const int ks = blockIdx.z % KSP;
  int bx, by;
  if (SWZ == 1) {
    int lin = (int)(blockIdx.x + gridDim.x * blockIdx.y);
    int wmt = 256 / (int)gridDim.x;  // m-tiles per 256-block window
    by = wmt * (lin >> 8) + ((lin & 255) % wmt);
    bx = (lin & 255) / wmt;
  } else if (SWZ == 2) {
    by = blockIdx.x;   // m-major
    bx = blockIdx.y;
  } else {
    bx = blockIdx.x;
    by = blockIdx.y;
  }

  const half_t* Xb = X + (long)zb * xbs + (long)ks * K;
  const half_t* Yb = Y + (long)zb * ybs + (long)ks * K;
  OutT* Cb = Co + (long)blockIdx.z * cbs;

  const int m0 = by * BM;
  const int n0 = bx * BN;
  const int tid = (int)threadIdx.x;
  const int wave = tid >> 6;
  const int lane = tid & 63;
  const int quad = lane >> 4;
  const int l16 = lane & 15;
  const int wm = wave >> 1;
  const int wn = wave & 1;

  floatx4 acc[SM][SN] = {};

  const int srow = lane / CPR;
  const int schunk = lane % CPR;
  const char* Xc = (const char*)Xb;

  // hoisted staging byte-offsets (per lane, per round), relative to Xb;
  // all operands live in one ws allocation -> diffs fit int32 (signed ok)
  int soff[ROUNDS];
#pragma unroll
  for (int r = 0; r < ROUNDS; ++r) {
    int row = r * (4 * RPW) + wave * RPW + srow;
    int gchunk = schunk ^ (row & (CPR - 1));
    const char* p = (row < BM)
        ? (const char*)(Xb + (long)(m0 + row) * ldx)
        : (const char*)(Yb + (long)(n0 + row - BM) * ldy);
    soff[r] = (int)(p + gchunk * 16 - Xc);
  }

  // hoisted fragment LDS byte offsets at kk=0 (relative to Sh)
  int offA[SM], offB[SN];
#pragma unroll
  for (int i = 0; i < SM; ++i) {
    int m = wm * (BM / 2) + i * 16 + l16;
    int cc = quad ^ (m & (CPR - 1));
    offA[i] = (m * BK + cc * 8) * 2;
  }
#pragma unroll
  for (int j = 0; j < SN; ++j) {
    int n = wn * (BN / 2) + j * 16 + l16;
    int cc = quad ^ (n & (CPR - 1));
    offB[j] = (BM * BK + n * BK + cc * 8) * 2;
  }

  for (int k0 = 0; k0 < K; k0 += BK) {
#pragma unroll
    for (int r = 0; r < ROUNDS; ++r) {
      gld16((char*)Sh + (r * 4 + wave) * 1024, Xc + (long)soff[r]);
      soff[r] += BK * 2;
    }
    __syncthreads();  // drains vmcnt(0): staging visible

#pragma unroll
    for (int kk = 0; kk < KSTEPS; ++kk) {
      const int kx = kk << 6;  // byte-XOR key for chunk swizzle
      half8 af[SM], bf[SN];
#pragma unroll
      for (int i = 0; i < SM; ++i)
        af[i] = *(const half8*)((const char*)Sh + (offA[i] ^ kx));
#pragma unroll
      for (int j = 0; j < SN; ++j)
        bf[j] = *(const half8*)((const char*)Sh + (offB[j] ^ kx));
#pragma unroll
      for (int i = 0; i < SM; ++i)
#pragma unroll
        for (int j = 0; j < SN; ++j)
          acc[i][j] = __builtin_amdgcn_mfma_f32_16x16x32_f16(af[i], bf[j], acc[i][j], 0, 0, 0);
    }
    __syncthreads();
  }

#pragma unroll
  for (int i = 0; i < SM; ++i) {
    int gmb = m0 + wm * (BM / 2) + i * 16 + quad * 4;
    float rs[4] = {0.f, 0.f, 0.f, 0.f};
#pragma unroll
    for (int j = 0; j < SN; ++j) {
      int gn = n0 + wn * (BN / 2) + j * 16 + l16;
      float bias = 0.f, sc = 1.f;
      if (EPI == 1) {
        if (gn < CH) { bias = b0[gn]; sc = scale; }
        else if (gn < 2 * CH) { bias = b1[gn - CH]; }
        else { bias = b2[gn - 2 * CH]; }
      } else if (EPI == 2) {
        bias = b0[gn];
      }
#pragma unroll
      for (int r = 0; r < 4; ++r) {
        long idx = (long)(gmb + r) * ldc + gn;
        float v = acc[i][j][r];
        if (EPI == 1) v = (v + bias) * sc;
        if (EPI == 2) v = v + bias + resid[idx];
        if (EPI == 3) { v = __expf(v); rs[r] += v; }
        Cb[idx] = (OutT)v;
      }
    }
    if (EPI == 3) {
#pragma unroll
      for (int r = 0; r < 4; ++r) {
        float v = rs[r];
        v += __shfl_xor(v, 1);
        v += __shfl_xor(v, 2);
        v += __shfl_xor(v, 4);
        v += __shfl_xor(v, 8);
        if (l16 == 0) atomicAdd(&rowsum[(long)zb * NSP + gmb + r], v);
      }
    }
  }
}

// ---------------- PV split-K combine: ao = (sum of slabs) / rowsum --------
__global__ __launch_bounds__(256) void pv_combine(const half_t* __restrict__ part,
                                                  const float* __restrict__ rowsum,
                                                  half_t* __restrict__ ao) {
  const long bNC = (long)NSP * CH;
  long i = ((long)blockIdx.x * 256 + threadIdx.x) * 8;
  int b = (int)(i >> 21);
  long inner = i & ((1L << 21) - 1);
  float inv = 1.f / rowsum[i >> 9];
  float s[8] = {};
#pragma unroll
  for (int ks = 0; ks < KSPLIT; ++ks) {
    half8 h = *(const half8*)(part + ((long)(b * KSPLIT + ks)) * bNC + inner);
#pragma unroll
    for (int r = 0; r < 8; ++r) s[r] += (float)h[r];
  }
  half8 o;
#pragma unroll
  for (int r = 0; r < 8; ++r) o[r] = (half_t)(s[r] * inv);
  *(half8*)(ao + i) = o;
}

extern "C" void kernel_launch(void* const* d_in, const int* in_sizes, int n_in,
                              void* d_out, int out_size, void* d_ws, size_t ws_size,
                              hipStream_t stream) {
  const float* x = (const float*)d_in[0];
  const float* gamma = (const float*)d_in[1];
  const float* beta = (const float*)d_in[2];
  const float* wq = (const float*)d_in[3];
  const float* bq = (const float*)d_in[4];
  const float* wk = (const float*)d_in[5];
  const float* bk = (const float*)d_in[6];
  const float* wv = (const float*)d_in[7];
  const float* bv = (const float*)d_in[8];
  const float* wp = (const float*)d_in[9];
  const float* bp = (const float*)d_in[10];
  float* out = (float*)d_out;
  char* ws = (char*)d_ws;

  float* st = (float*)(ws + OFF_STATS);
  float* rsum = (float*)(ws + OFF_ROWSUM);   // [BATCH][NSP]
  float* pst = (float*)(ws + OFF_PST);       // GN chunk partials
  half_t* wqkvT = (half_t*)(ws + OFF_WQKV);  // [1536][512]
  half_t* wpT = (half_t*)(ws + OFF_WP);
  half_t* xn = (half_t*)(ws + OFF_XN);
  half_t* qkv = (half_t*)(ws + OFF_QKV);     // [B*4096][1536]
  half_t* vt = (half_t*)(ws + OFF_VT);
  half_t* ao = (half_t*)(ws + OFF_AO);
  half_t* S = (half_t*)(ws + OFF_S);
  half_t* part = (half_t*)(ws + OFF_PART);   // 8 x 4MB PV partial slabs

  half_t* q = qkv;            // ld NQKV
  half_t* k = qkv + CH;       // ld NQKV
  half_t* v = qkv + 2 * CH;   // ld NQKV

  const float scale = 0.044194173824159216f;  // 1/sqrt(512)
  const long bQKV = (long)NSP * NQKV;
  const long bNC = (long)NSP * CH;
  const long bNN = (long)NSP * NSP;

  gn_stats<<<dim3(256, BATCH), 256, 0, stream>>>(x, pst);
  gn_finalize<<<1, 256, 0, stream>>>(pst, st, rsum);
  gn_apply<<<2048, 256, 0, stream>>>(x, st, gamma, beta, xn);
  transpose_w<<<dim3(16, 16, 4), 256, 0, stream>>>(
      wq, wk, wv, wp, wqkvT, wqkvT + (size_t)CH * CH, wqkvT + 2 * (size_t)CH * CH, wpT);

  // fused qkv = xn @ [wq|wk|wv]^T + bias (q scaled): 128x128 BK=64,
  // m-major grid (64,12) -> xn panels XCD-local
  gemm_nt<128, 128, 64, 1, 2, 1, half_t><<<dim3(BATCH * NSP / 128, NQKV / 128, 1), 256, 0, stream>>>(
      xn, wqkvT, qkv, bq, bk, bv, nullptr, nullptr, BATCH * NSP, NQKV, CH,
      CH, CH, NQKV, 0, 0, 0, scale);
  transpose_v<<<dim3(16, 128, BATCH), 256, 0, stream>>>(v, vt);

  bool full = ws_size >= OFF_S + 2 * S_BYTES_1;
  if (full) {
    // scores -> exp(s) + row sums: 128x128 BK=64 + window swizzle, (32,32,2)
    gemm_nt<128, 128, 64, 3, 1, 1, half_t><<<dim3(32, 32, BATCH), 256, 0, stream>>>(
        q, k, S, nullptr, nullptr, nullptr, nullptr, rsum, NSP, NSP, CH,
        NQKV, NQKV, NSP, bQKV, bQKV, bNN, 1.f);
    // PV split-K: 128x128 BK=64, K=1024/split, m-major (32,4,8) = 1024 blocks
    gemm_nt<128, 128, 64, 0, 2, KSPLIT, half_t><<<dim3(NSP / 128, CH / 128, BATCH * KSPLIT), 256, 0, stream>>>(
        S, vt, part, nullptr, nullptr, nullptr, nullptr, nullptr, NSP, CH, NSP / KSPLIT,
        NSP, NSP, CH, bNN, bNC, bNC, 1.f);
    pv_combine<<<2048, 256, 0, stream>>>(part, rsum, ao);
  } else {
    for (int bb = 0; bb < BATCH; ++bb) {
      gemm_nt<128, 128, 64, 3, 1, 1, half_t><<<dim3(32, 32, 1), 256, 0, stream>>>(
          q + bb * bQKV, k + bb * bQKV, S, nullptr, nullptr, nullptr, nullptr,
          rsum + bb * NSP, NSP, NSP, CH, NQKV, NQKV, NSP, 0, 0, 0, 1.f);
      gemm_nt<128, 128, 64, 0, 2, KSPLIT, half_t><<<dim3(NSP / 128, CH / 128, KSPLIT), 256, 0, stream>>>(
          S, vt + bb * bNC, part + (long)bb * KSPLIT * bNC, nullptr, nullptr, nullptr,
          nullptr, nullptr, NSP, CH, NSP / KSPLIT, NSP, NSP, CH, 0, 0, bNC, 1.f);
    }
    pv_combine<<<2048, 256, 0, stream>>>(part, rsum, ao);
  }
  // out = ao @ wp^T + bp + x : 64x64 BK=128, m-major (128,8)
  gemm_nt<64, 64, 128, 2, 2, 1, float><<<dim3(BATCH * NSP / 64, CH / 64, 1), 256, 0, stream>>>(
      ao, wpT, out, bp, nullptr, nullptr, x, nullptr, BATCH * NSP, CH, CH,
      CH, CH, CH, 0, 0, 0, 1.f);
}